// Round 1
// baseline (1626.997 us; speedup 1.0000x reference)
//
#include <hip/hip_runtime.h>
#include <math.h>

// RationalQuadraticSpline: fused MLP (64->64->128->1600) + RQ spline.
// Round 0: correct fp32 baseline, fully fused (params never hit HBM).
// Block = 16 rows x 256 threads. Grid = 65536/16 = 4096 blocks.

namespace {

constexpr int ROWS = 16;
constexpr int NTHR = 256;
constexpr int FGRP = 4;       // features per spline batch
constexpr float TBOUND = 3.0f;

__global__ __launch_bounds__(NTHR) void rqs_fused(
    const float* __restrict__ x,    // [B,64]
    const float* __restrict__ W1,   // [64,64]
    const float* __restrict__ b1,   // [64]
    const float* __restrict__ W2,   // [64,128]
    const float* __restrict__ b2,   // [128]
    const float* __restrict__ W3,   // [128,1600]
    const float* __restrict__ b3,   // [1600]
    float* __restrict__ out,        // [B,64]
    float* __restrict__ ldet)       // [B]
{
  __shared__ float xs[ROWS][64];        // 4 KB
  __shared__ float h1s[ROWS][64];       // 4 KB
  __shared__ float h2s[ROWS][132];      // 8.25 KB (pad 132: bank spread)
  __shared__ float w3t[25][132];        // 12.9 KB transposed W3 chunk
  __shared__ float ps[FGRP][ROWS][27];  // params, pad 27
  __shared__ float ys[ROWS][68];        // output staging, pad 68
  __shared__ float ldp[FGRP][ROWS];     // log_det partials (deterministic)

  const int t = threadIdx.x;
  const int row0 = blockIdx.x * ROWS;

  // ---- load x rows ----
  for (int i = t; i < ROWS * 64; i += NTHR) {
    int r = i >> 6, c = i & 63;
    xs[r][c] = x[(size_t)(row0 + r) * 64 + c];
  }
  if (t < FGRP * ROWS) ldp[t >> 4][t & 15] = 0.f;
  __syncthreads();

  // ---- h1 = relu(x @ W1 + b1): thread = (col, 4-row group) ----
  {
    const int c = t & 63;
    const int rg = (t >> 6) * 4;
    float a0 = 0.f, a1 = 0.f, a2 = 0.f, a3 = 0.f;
    for (int k = 0; k < 64; ++k) {
      float w = W1[k * 64 + c];        // coalesced, L1-hot
      a0 = fmaf(xs[rg + 0][k], w, a0); // LDS broadcast
      a1 = fmaf(xs[rg + 1][k], w, a1);
      a2 = fmaf(xs[rg + 2][k], w, a2);
      a3 = fmaf(xs[rg + 3][k], w, a3);
    }
    float bb = b1[c];
    h1s[rg + 0][c] = fmaxf(a0 + bb, 0.f);
    h1s[rg + 1][c] = fmaxf(a1 + bb, 0.f);
    h1s[rg + 2][c] = fmaxf(a2 + bb, 0.f);
    h1s[rg + 3][c] = fmaxf(a3 + bb, 0.f);
  }
  __syncthreads();

  // ---- h2 = relu(h1 @ W2 + b2): thread = (col of 128, 8-row group) ----
  {
    const int c = t & 127;
    const int rg = (t >> 7) * 8;
    float acc[8];
#pragma unroll
    for (int j = 0; j < 8; ++j) acc[j] = 0.f;
    for (int k = 0; k < 64; ++k) {
      float w = W2[k * 128 + c];
#pragma unroll
      for (int j = 0; j < 8; ++j) acc[j] = fmaf(h1s[rg + j][k], w, acc[j]);
    }
    float bb = b2[c];
#pragma unroll
    for (int j = 0; j < 8; ++j) h2s[rg + j][c] = fmaxf(acc[j] + bb, 0.f);
  }
  __syncthreads();

  // ---- phase 2: per feature, params = h2 @ W3[:,f*25:f*25+25] + b3, then spline ----
  for (int fg = 0; fg < 64 / FGRP; ++fg) {
#pragma unroll 1
    for (int fi = 0; fi < FGRP; ++fi) {
      const int f = fg * FGRP + fi;
      __syncthreads();  // protect w3t (prev readers) and ps (prev spline readers)
      // stage W3 chunk transposed: w3t[p][k] = W3[k][f*25+p]; global reads coalesced
      for (int i = t; i < 25 * 128; i += NTHR) {
        int k = i / 25;
        int p = i - k * 25;
        w3t[p][k] = W3[(size_t)k * 1600 + f * 25 + p];
      }
      __syncthreads();
      // 400 dots (25 p x 16 r), 200 threads, 2-row register tile, float4 LDS reads
      if (t < 200) {
        const int p = t >> 3;
        const int r = t & 7;
        float a0 = 0.f, a1 = 0.f;
        const float* wp  = &w3t[p][0];
        const float* hp0 = &h2s[r][0];
        const float* hp1 = &h2s[r + 8][0];
#pragma unroll 8
        for (int k = 0; k < 128; k += 4) {
          float4 wv = *(const float4*)(wp + k);
          float4 u  = *(const float4*)(hp0 + k);
          float4 v  = *(const float4*)(hp1 + k);
          a0 = fmaf(wv.x, u.x, a0); a0 = fmaf(wv.y, u.y, a0);
          a0 = fmaf(wv.z, u.z, a0); a0 = fmaf(wv.w, u.w, a0);
          a1 = fmaf(wv.x, v.x, a1); a1 = fmaf(wv.y, v.y, a1);
          a1 = fmaf(wv.z, v.z, a1); a1 = fmaf(wv.w, v.w, a1);
        }
        float bb = b3[f * 25 + p];
        ps[fi][r][p]     = a0 + bb;
        ps[fi][r + 8][p] = a1 + bb;
      }
    }
    __syncthreads();  // ps complete for FGRP features
    // ---- spline: 64 lanes, one (row, feature) each ----
    if (t < FGRP * ROWS) {
      const int fi = t >> 4;
      const int r = t & 15;
      const int f = fg * FGRP + fi;
      const float* pp = &ps[fi][r][0];
      const float xv = xs[r][f];

      float we[8], hh[8], dd[9];
      // widths = softmax(pp[0:8]) * 2*TB*(1-K*MW) + MW  (scale = 6*0.992 = 5.952)
      float m = pp[0];
#pragma unroll
      for (int j = 1; j < 8; ++j) m = fmaxf(m, pp[j]);
      float s = 0.f;
#pragma unroll
      for (int j = 0; j < 8; ++j) { we[j] = __expf(pp[j] - m); s += we[j]; }
      float sc = 5.952f / s;
#pragma unroll
      for (int j = 0; j < 8; ++j) we[j] = we[j] * sc + 0.001f;
      // heights = softmax(pp[8:16]) * 5.952 + 0.001
      m = pp[8];
#pragma unroll
      for (int j = 1; j < 8; ++j) m = fmaxf(m, pp[8 + j]);
      s = 0.f;
#pragma unroll
      for (int j = 0; j < 8; ++j) { hh[j] = __expf(pp[8 + j] - m); s += hh[j]; }
      sc = 5.952f / s;
#pragma unroll
      for (int j = 0; j < 8; ++j) hh[j] = hh[j] * sc + 0.001f;
      // derivs = softplus(pp[16:25]) + MD
#pragma unroll
      for (int j = 0; j < 9; ++j) {
        float v = pp[16 + j];
        dd[j] = fmaxf(v, 0.f) + __logf(1.f + __expf(-fabsf(v))) + 0.001f;
      }

      const bool inside = (xv >= -TBOUND) && (xv <= TBOUND);
      const float xc = fminf(fmaxf(xv, -TBOUND), TBOUND);

      // bin walk: bin = max{j<=7 : cumw[j] <= xc} (matches count-1 clipped)
      float cw = -TBOUND + we[0];
      float ch = -TBOUND + hh[0];
      float cwk = -TBOUND, chk = -TBOUND;
      float wk = we[0], hk = hh[0], dk = dd[0], dk1 = dd[1];
#pragma unroll
      for (int j = 1; j < 8; ++j) {
        bool g = (cw <= xc);
        cwk = g ? cw : cwk;
        chk = g ? ch : chk;
        wk  = g ? we[j] : wk;
        hk  = g ? hh[j] : hk;
        dk  = g ? dd[j] : dk;
        dk1 = g ? dd[j + 1] : dk1;
        cw += we[j];
        ch += hh[j];
      }

      float th = (xc - cwk) / wk;
      float om = 1.f - th;
      float th2 = th * th, thom = th * om, om2 = om * om;
      float num = hk * (dk * th2 + dk1 * thom);
      float den = dk * th2 + 2.f * dk1 * thom + dk1 * om2;
      float yv = chk + num / den;
      float dn = dk1 * th2 + 2.f * dk * thom + dk * om2;
      float ld = 2.f * __logf(dn) - 2.f * __logf(den) + __logf(hk) - __logf(wk);

      ys[r][f] = inside ? yv : xv;
      ldp[fi][r] += inside ? ld : 0.f;   // same thread each fg: deterministic
    }
  }
  __syncthreads();

  // ---- epilogue: coalesced output writes ----
  if (t < ROWS) {
    ldet[row0 + t] = ldp[0][t] + ldp[1][t] + ldp[2][t] + ldp[3][t];
  }
  for (int i = t; i < ROWS * 64; i += NTHR) {
    int r = i >> 6, c = i & 63;
    out[(size_t)(row0 + r) * 64 + c] = ys[r][c];
  }
}

}  // namespace

extern "C" void kernel_launch(void* const* d_in, const int* in_sizes, int n_in,
                              void* d_out, int out_size, void* d_ws, size_t ws_size,
                              hipStream_t stream) {
  const float* x  = (const float*)d_in[0];
  const float* W1 = (const float*)d_in[1];
  const float* b1 = (const float*)d_in[2];
  const float* W2 = (const float*)d_in[3];
  const float* b2 = (const float*)d_in[4];
  const float* W3 = (const float*)d_in[5];
  const float* b3 = (const float*)d_in[6];
  float* out = (float*)d_out;
  float* ldet = out + (size_t)65536 * 64;

  dim3 grid(65536 / ROWS);
  rqs_fused<<<grid, NTHR, 0, stream>>>(x, W1, b1, W2, b2, W3, b3, out, ldet);
}

// Round 6
// 769.621 us; speedup vs baseline: 2.1140x; 2.1140x over previous
//
#include <hip/hip_runtime.h>
#include <math.h>

// RationalQuadraticSpline: fused MLP (64->64->128->1600) + RQ spline.
// R5: ldet's log-derivative is DISCONTINUOUS at bin boundaries -> bin decisions
// must match the reference's fp32 decisions; MFMA accumulation topology causes
// near-boundary bin flips with O(1) ldet jumps (R3==R4==3.5 precision-independent
// floor). So GEMM3 keeps R0's exact fp32 sequential-fmaf numerics (bitwise),
// restructured for speed: 4 rows x 25 params per thread in registers, W3 via
// LDS slab, spline computed directly from registers (no params LDS roundtrip).

namespace {

constexpr int NTHR = 128;
constexpr int ROWS = 32;
constexpr float TBOUND = 3.0f;

typedef __attribute__((ext_vector_type(4))) float f32x4v;

__global__ __launch_bounds__(NTHR) void rqs_fused(
    const float* __restrict__ x, const float* __restrict__ W1,
    const float* __restrict__ b1, const float* __restrict__ W2,
    const float* __restrict__ b2, const float* __restrict__ W3,
    const float* __restrict__ b3, float* __restrict__ out,
    float* __restrict__ ldet) {
  __shared__ float xs[ROWS][68];    // x in; y written in-place per (r,f)
  __shared__ float h1s[ROWS][68];
  __shared__ float h2s[ROWS][132];
  __shared__ float slab[8][448];    // 8 k-rows x (16 f x 28 pad) of W3
  __shared__ float ldp[ROWS][17];

  const int t = threadIdx.x;
  const int row0 = blockIdx.x * ROWS;

  for (int i = t; i < ROWS * 64; i += NTHR) {
    int r = i >> 6, c = i & 63;
    xs[r][c] = x[(size_t)(row0 + r) * 64 + c];
  }
  for (int i = t; i < ROWS * 17; i += NTHR) ((float*)ldp)[i] = 0.f;
  __syncthreads();

  // ---- GEMM1: h1 = relu(x @ W1 + b1); k ascending fmaf chain (R0-bitwise) ----
  {
    const int c = t & 63;
    const int rg = (t >> 6) * 16;
    float acc[16];
#pragma unroll
    for (int j = 0; j < 16; ++j) acc[j] = 0.f;
    for (int k4 = 0; k4 < 16; ++k4) {
      float w0 = W1[(k4 * 4 + 0) * 64 + c];
      float w1 = W1[(k4 * 4 + 1) * 64 + c];
      float w2 = W1[(k4 * 4 + 2) * 64 + c];
      float w3v = W1[(k4 * 4 + 3) * 64 + c];
#pragma unroll
      for (int j = 0; j < 16; ++j) {
        f32x4v xv = *(const f32x4v*)&xs[rg + j][k4 * 4];
        acc[j] = fmaf(xv[0], w0, acc[j]);
        acc[j] = fmaf(xv[1], w1, acc[j]);
        acc[j] = fmaf(xv[2], w2, acc[j]);
        acc[j] = fmaf(xv[3], w3v, acc[j]);
      }
    }
    float bb = b1[c];
#pragma unroll
    for (int j = 0; j < 16; ++j)
      h1s[rg + j][c] = fmaxf(acc[j] + bb, 0.f);
  }
  __syncthreads();

  // ---- GEMM2: h2 = relu(h1 @ W2 + b2); 2 cols x 16 rows per thread ----
  {
    const int c2 = t & 63;
    const int rg = (t >> 6) * 16;
    float a0[16], a1[16];
#pragma unroll
    for (int j = 0; j < 16; ++j) { a0[j] = 0.f; a1[j] = 0.f; }
    for (int k4 = 0; k4 < 16; ++k4) {
      float w00 = W2[(k4 * 4 + 0) * 128 + c2], w10 = W2[(k4 * 4 + 0) * 128 + c2 + 64];
      float w01 = W2[(k4 * 4 + 1) * 128 + c2], w11 = W2[(k4 * 4 + 1) * 128 + c2 + 64];
      float w02 = W2[(k4 * 4 + 2) * 128 + c2], w12 = W2[(k4 * 4 + 2) * 128 + c2 + 64];
      float w03 = W2[(k4 * 4 + 3) * 128 + c2], w13 = W2[(k4 * 4 + 3) * 128 + c2 + 64];
#pragma unroll
      for (int j = 0; j < 16; ++j) {
        f32x4v hv = *(const f32x4v*)&h1s[rg + j][k4 * 4];
        a0[j] = fmaf(hv[0], w00, a0[j]);
        a0[j] = fmaf(hv[1], w01, a0[j]);
        a0[j] = fmaf(hv[2], w02, a0[j]);
        a0[j] = fmaf(hv[3], w03, a0[j]);
        a1[j] = fmaf(hv[0], w10, a1[j]);
        a1[j] = fmaf(hv[1], w11, a1[j]);
        a1[j] = fmaf(hv[2], w12, a1[j]);
        a1[j] = fmaf(hv[3], w13, a1[j]);
      }
    }
    float bb0 = b2[c2], bb1 = b2[c2 + 64];
#pragma unroll
    for (int j = 0; j < 16; ++j) {
      h2s[rg + j][c2] = fmaxf(a0[j] + bb0, 0.f);
      h2s[rg + j][c2 + 64] = fmaxf(a1[j] + bb1, 0.f);
    }
  }
  __syncthreads();

  // ---- GEMM3 + spline: thread = (rgrp in [0,8) -> 4 rows, f in [0,16)) ----
  const int f = t & 15;
  const int rgrp = t >> 4;

#pragma unroll 1
  for (int ch = 0; ch < 4; ++ch) {
    float acc[4][25];
#pragma unroll
    for (int j = 0; j < 4; ++j)
#pragma unroll
      for (int p = 0; p < 25; ++p) acc[j][p] = 0.f;

#pragma unroll 1
    for (int ks = 0; ks < 16; ++ks) {
      __syncthreads();  // prev slab readers done
      // stage W3[ks*8 .. ks*8+8)[ch*400 .. +400) -> slab[kk][ff*28+p]
#pragma unroll
      for (int q = 0; q < 25; ++q) {
        int i = t + q * NTHR;
        int kk = i / 400;
        int col = i - kk * 400;
        int ff = col / 25;
        int p = col - ff * 25;
        slab[kk][ff * 28 + p] = W3[(size_t)(ks * 8 + kk) * 1600 + ch * 400 + col];
      }
      __syncthreads();
#pragma unroll
      for (int kq = 0; kq < 2; ++kq) {
        f32x4v ha0 = *(const f32x4v*)&h2s[rgrp * 4 + 0][ks * 8 + kq * 4];
        f32x4v ha1 = *(const f32x4v*)&h2s[rgrp * 4 + 1][ks * 8 + kq * 4];
        f32x4v ha2 = *(const f32x4v*)&h2s[rgrp * 4 + 2][ks * 8 + kq * 4];
        f32x4v ha3 = *(const f32x4v*)&h2s[rgrp * 4 + 3][ks * 8 + kq * 4];
#pragma unroll
        for (int e = 0; e < 4; ++e) {
          f32x4v w4[7];
#pragma unroll
          for (int q = 0; q < 7; ++q)
            w4[q] = *(const f32x4v*)&slab[kq * 4 + e][f * 28 + q * 4];
#pragma unroll
          for (int p = 0; p < 25; ++p) {
            float wv = w4[p >> 2][p & 3];
            acc[0][p] = fmaf(ha0[e], wv, acc[0][p]);
            acc[1][p] = fmaf(ha1[e], wv, acc[1][p]);
            acc[2][p] = fmaf(ha2[e], wv, acc[2][p]);
            acc[3][p] = fmaf(ha3[e], wv, acc[3][p]);
          }
        }
      }
    }

    // bias then spline for this thread's 4 rows, straight from registers
    float b3v[25];
#pragma unroll
    for (int p = 0; p < 25; ++p) b3v[p] = b3[ch * 400 + f * 25 + p];
#pragma unroll
    for (int j = 0; j < 4; ++j) {
      const int r = rgrp * 4 + j;
      float pp[25];
#pragma unroll
      for (int p = 0; p < 25; ++p) pp[p] = acc[j][p] + b3v[p];
      const float xv = xs[r][ch * 16 + f];

      float we[8], hh[8], dd[9];
      float m = pp[0];
#pragma unroll
      for (int q = 1; q < 8; ++q) m = fmaxf(m, pp[q]);
      float s = 0.f;
#pragma unroll
      for (int q = 0; q < 8; ++q) { we[q] = __expf(pp[q] - m); s += we[q]; }
      float sc = 5.952f / s;
#pragma unroll
      for (int q = 0; q < 8; ++q) we[q] = we[q] * sc + 0.001f;
      m = pp[8];
#pragma unroll
      for (int q = 1; q < 8; ++q) m = fmaxf(m, pp[8 + q]);
      s = 0.f;
#pragma unroll
      for (int q = 0; q < 8; ++q) { hh[q] = __expf(pp[8 + q] - m); s += hh[q]; }
      sc = 5.952f / s;
#pragma unroll
      for (int q = 0; q < 8; ++q) hh[q] = hh[q] * sc + 0.001f;
#pragma unroll
      for (int q = 0; q < 9; ++q) {
        float v = pp[16 + q];
        dd[q] = fmaxf(v, 0.f) + __logf(1.f + __expf(-fabsf(v))) + 0.001f;
      }

      const bool inside = (xv >= -TBOUND) && (xv <= TBOUND);
      const float xc = fminf(fmaxf(xv, -TBOUND), TBOUND);

      float cw = -TBOUND + we[0];
      float chh = -TBOUND + hh[0];
      float cwk = -TBOUND, chk = -TBOUND;
      float wk = we[0], hk = hh[0], dk = dd[0], dk1 = dd[1];
#pragma unroll
      for (int q = 1; q < 8; ++q) {
        bool g = (cw <= xc);
        cwk = g ? cw : cwk;
        chk = g ? chh : chk;
        wk = g ? we[q] : wk;
        hk = g ? hh[q] : hk;
        dk = g ? dd[q] : dk;
        dk1 = g ? dd[q + 1] : dk1;
        cw += we[q];
        chh += hh[q];
      }

      float th = (xc - cwk) / wk;
      float om = 1.f - th;
      float th2 = th * th, thom = th * om, om2 = om * om;
      float num = hk * (dk * th2 + dk1 * thom);
      float den = dk * th2 + 2.f * dk1 * thom + dk1 * om2;
      float yv = chk + num / den;
      float dn = dk1 * th2 + 2.f * dk * thom + dk * om2;
      float ld = 2.f * __logf(dn) - 2.f * __logf(den) + __logf(hk) - __logf(wk);

      xs[r][ch * 16 + f] = inside ? yv : xv;   // y in-place (own slot)
      ldp[r][f] += inside ? ld : 0.f;          // own slot, deterministic
    }
  }
  __syncthreads();

  // ---- epilogue ----
  if (t < ROWS) {
    float s = 0.f;
#pragma unroll
    for (int q = 0; q < 16; ++q) s += ldp[t][q];
    ldet[row0 + t] = s;
  }
  for (int i = t; i < ROWS * 64; i += NTHR) {
    int r = i >> 6, c = i & 63;
    out[(size_t)(row0 + r) * 64 + c] = xs[r][c];
  }
}

}  // namespace

extern "C" void kernel_launch(void* const* d_in, const int* in_sizes, int n_in,
                              void* d_out, int out_size, void* d_ws, size_t ws_size,
                              hipStream_t stream) {
  const float* x = (const float*)d_in[0];
  const float* W1 = (const float*)d_in[1];
  const float* b1 = (const float*)d_in[2];
  const float* W2 = (const float*)d_in[3];
  const float* b2 = (const float*)d_in[4];
  const float* W3 = (const float*)d_in[5];
  const float* b3 = (const float*)d_in[6];
  float* out = (float*)d_out;
  float* ldet = out + (size_t)65536 * 64;

  rqs_fused<<<dim3(65536 / ROWS), dim3(NTHR), 0, stream>>>(
      x, W1, b1, W2, b2, W3, b3, out, ldet);
}

// Round 7
// 616.311 us; speedup vs baseline: 2.6399x; 1.2488x over previous
//
#include <hip/hip_runtime.h>
#include <math.h>

// RationalQuadraticSpline: fused MLP (64->64->128->1600) + RQ spline.
// R6: fp32 numerics kept (MFMA bin-flip issue, see R5). Occupancy/latency attack:
//  - 64 rows x 256 thr (4 rows/thread), 1024 blocks
//  - LDS arena: uni = union(h1s, slab double-buffer) -> 79.9 KB, 2 blocks/CU
//  - slab double-buffered, register-prefetched (issue-early/write-late)
//  - precomputed packed staging offsets (no per-round int divides)
//  - ldet partials in registers, shfl_xor width-16 reduce

namespace {

constexpr int NTHR = 256;
constexpr int ROWS = 64;
constexpr float TBOUND = 3.0f;

typedef __attribute__((ext_vector_type(4))) float f32x4v;

#define PREFETCH_SLAB(CH, KS)                                              \
  do {                                                                     \
    const float* wsrc = W3 + (size_t)(KS)*12800 + (CH)*400;                \
    _Pragma("unroll") for (int q = 0; q < 12; ++q) pf[q] =                 \
        wsrc[pk[q] >> 12];                                                 \
    if (t < 128) pf[12] = wsrc[pk[12] >> 12];                              \
  } while (0)

#define WRITE_SLAB(SB)                                                     \
  do {                                                                     \
    _Pragma("unroll") for (int q = 0; q < 12; ++q)                         \
        uni[(SB) + (pk[q] & 4095)] = pf[q];                                \
    if (t < 128) uni[(SB) + (pk[12] & 4095)] = pf[12];                     \
  } while (0)

__global__ __launch_bounds__(NTHR) void rqs_fused(
    const float* __restrict__ x, const float* __restrict__ W1,
    const float* __restrict__ b1, const float* __restrict__ W2,
    const float* __restrict__ b2, const float* __restrict__ W3,
    const float* __restrict__ b3, float* __restrict__ out,
    float* __restrict__ ldet) {
  __shared__ float xs[ROWS][68];     // x in; y written in-place
  __shared__ float h2s[ROWS][132];
  __shared__ float uni[7168];        // GEMM1/2: h1s[64][68]; GEMM3: slab[2][8][448]

  const int t = threadIdx.x;
  const int row0 = blockIdx.x * ROWS;

  for (int i = t; i < ROWS * 64; i += NTHR) {
    int r = i >> 6, c = i & 63;
    xs[r][c] = x[(size_t)(row0 + r) * 64 + c];
  }
  __syncthreads();

  // ---- GEMM1: h1 = relu(x @ W1 + b1); 1 col x 16 rows/thread ----
  {
    const int c = t & 63;
    const int rg = (t >> 6) * 16;
    float acc[16];
#pragma unroll
    for (int j = 0; j < 16; ++j) acc[j] = 0.f;
    for (int k4 = 0; k4 < 16; ++k4) {
      float w0 = W1[(k4 * 4 + 0) * 64 + c];
      float w1 = W1[(k4 * 4 + 1) * 64 + c];
      float w2 = W1[(k4 * 4 + 2) * 64 + c];
      float w3v = W1[(k4 * 4 + 3) * 64 + c];
#pragma unroll
      for (int j = 0; j < 16; ++j) {
        f32x4v xv = *(const f32x4v*)&xs[rg + j][k4 * 4];
        acc[j] = fmaf(xv[0], w0, acc[j]);
        acc[j] = fmaf(xv[1], w1, acc[j]);
        acc[j] = fmaf(xv[2], w2, acc[j]);
        acc[j] = fmaf(xv[3], w3v, acc[j]);
      }
    }
    float bb = b1[c];
#pragma unroll
    for (int j = 0; j < 16; ++j)
      uni[(rg + j) * 68 + c] = fmaxf(acc[j] + bb, 0.f);
  }
  __syncthreads();

  // ---- GEMM2: h2 = relu(h1 @ W2 + b2); 2 cols x 16 rows/thread ----
  {
    const int c2 = t & 63;
    const int rg = (t >> 6) * 16;
    float a0[16], a1[16];
#pragma unroll
    for (int j = 0; j < 16; ++j) { a0[j] = 0.f; a1[j] = 0.f; }
    for (int k4 = 0; k4 < 16; ++k4) {
      float w00 = W2[(k4 * 4 + 0) * 128 + c2], w10 = W2[(k4 * 4 + 0) * 128 + c2 + 64];
      float w01 = W2[(k4 * 4 + 1) * 128 + c2], w11 = W2[(k4 * 4 + 1) * 128 + c2 + 64];
      float w02 = W2[(k4 * 4 + 2) * 128 + c2], w12 = W2[(k4 * 4 + 2) * 128 + c2 + 64];
      float w03 = W2[(k4 * 4 + 3) * 128 + c2], w13 = W2[(k4 * 4 + 3) * 128 + c2 + 64];
#pragma unroll
      for (int j = 0; j < 16; ++j) {
        f32x4v hv = *(const f32x4v*)&uni[(rg + j) * 68 + k4 * 4];
        a0[j] = fmaf(hv[0], w00, a0[j]);
        a0[j] = fmaf(hv[1], w01, a0[j]);
        a0[j] = fmaf(hv[2], w02, a0[j]);
        a0[j] = fmaf(hv[3], w03, a0[j]);
        a1[j] = fmaf(hv[0], w10, a1[j]);
        a1[j] = fmaf(hv[1], w11, a1[j]);
        a1[j] = fmaf(hv[2], w12, a1[j]);
        a1[j] = fmaf(hv[3], w13, a1[j]);
      }
    }
    float bb0 = b2[c2], bb1 = b2[c2 + 64];
#pragma unroll
    for (int j = 0; j < 16; ++j) {
      h2s[rg + j][c2] = fmaxf(a0[j] + bb0, 0.f);
      h2s[rg + j][c2 + 64] = fmaxf(a1[j] + bb1, 0.f);
    }
  }
  __syncthreads();   // h1s dead; uni becomes slab double-buffer

  // ---- GEMM3 + spline: thread = (rgrp in [0,16) -> 4 rows, f in [0,16)) ----
  const int f = t & 15;
  const int rgrp = t >> 4;

  // packed staging offsets: i = t + q*256 -> lds off (12b) | global off (14b)
  int pk[13];
#pragma unroll
  for (int q = 0; q < 13; ++q) {
    int i = t + q * 256;
    int kk = i / 400;
    int col = i - kk * 400;
    int ff = col / 25;
    int p = col - ff * 25;
    pk[q] = ((kk * 1600 + col) << 12) | (kk * 448 + ff * 28 + p);
  }

  float ldacc[4] = {0.f, 0.f, 0.f, 0.f};
  float pf[13];
  PREFETCH_SLAB(0, 0);

#pragma unroll 1
  for (int ch = 0; ch < 4; ++ch) {
    float acc[4][25];
#pragma unroll
    for (int j = 0; j < 4; ++j)
#pragma unroll
      for (int p = 0; p < 25; ++p) acc[j][p] = 0.f;

#pragma unroll 1
    for (int ks = 0; ks < 16; ++ks) {
      __syncthreads();                 // buf[ks&1] readers (iter ks-2) done
      const int sb = (ks & 1) * 3584;
      WRITE_SLAB(sb);
      if (ks < 15) {
        PREFETCH_SLAB(ch, ks + 1);     // hide L2 latency under compute
      } else if (ch < 3) {
        PREFETCH_SLAB(ch + 1, 0);      // next chunk's first slab under spline
      }
      __syncthreads();                 // slab writes visible

#pragma unroll
      for (int kq = 0; kq < 2; ++kq) {
        f32x4v ha0 = *(const f32x4v*)&h2s[rgrp * 4 + 0][ks * 8 + kq * 4];
        f32x4v ha1 = *(const f32x4v*)&h2s[rgrp * 4 + 1][ks * 8 + kq * 4];
        f32x4v ha2 = *(const f32x4v*)&h2s[rgrp * 4 + 2][ks * 8 + kq * 4];
        f32x4v ha3 = *(const f32x4v*)&h2s[rgrp * 4 + 3][ks * 8 + kq * 4];
#pragma unroll
        for (int e = 0; e < 4; ++e) {
          f32x4v w4[7];
#pragma unroll
          for (int q7 = 0; q7 < 7; ++q7)
            w4[q7] = *(const f32x4v*)&uni[sb + (kq * 4 + e) * 448 + f * 28 + q7 * 4];
#pragma unroll
          for (int p = 0; p < 25; ++p) {
            float wv = w4[p >> 2][p & 3];
            acc[0][p] = fmaf(ha0[e], wv, acc[0][p]);
            acc[1][p] = fmaf(ha1[e], wv, acc[1][p]);
            acc[2][p] = fmaf(ha2[e], wv, acc[2][p]);
            acc[3][p] = fmaf(ha3[e], wv, acc[3][p]);
          }
        }
      }
    }

    // ---- bias + spline for this thread's 4 rows, straight from registers ----
    float b3v[25];
#pragma unroll
    for (int p = 0; p < 25; ++p) b3v[p] = b3[ch * 400 + f * 25 + p];
#pragma unroll
    for (int j = 0; j < 4; ++j) {
      const int r = rgrp * 4 + j;
      float pp[25];
#pragma unroll
      for (int p = 0; p < 25; ++p) pp[p] = acc[j][p] + b3v[p];
      const float xv = xs[r][ch * 16 + f];

      float we[8], hh[8], dd[9];
      float m = pp[0];
#pragma unroll
      for (int q = 1; q < 8; ++q) m = fmaxf(m, pp[q]);
      float s = 0.f;
#pragma unroll
      for (int q = 0; q < 8; ++q) { we[q] = __expf(pp[q] - m); s += we[q]; }
      float sc = 5.952f / s;
#pragma unroll
      for (int q = 0; q < 8; ++q) we[q] = we[q] * sc + 0.001f;
      m = pp[8];
#pragma unroll
      for (int q = 1; q < 8; ++q) m = fmaxf(m, pp[8 + q]);
      s = 0.f;
#pragma unroll
      for (int q = 0; q < 8; ++q) { hh[q] = __expf(pp[8 + q] - m); s += hh[q]; }
      sc = 5.952f / s;
#pragma unroll
      for (int q = 0; q < 8; ++q) hh[q] = hh[q] * sc + 0.001f;
#pragma unroll
      for (int q = 0; q < 9; ++q) {
        float v = pp[16 + q];
        dd[q] = fmaxf(v, 0.f) + __logf(1.f + __expf(-fabsf(v))) + 0.001f;
      }

      const bool inside = (xv >= -TBOUND) && (xv <= TBOUND);
      const float xc = fminf(fmaxf(xv, -TBOUND), TBOUND);

      float cw = -TBOUND + we[0];
      float chh = -TBOUND + hh[0];
      float cwk = -TBOUND, chk = -TBOUND;
      float wk = we[0], hk = hh[0], dk = dd[0], dk1 = dd[1];
#pragma unroll
      for (int q = 1; q < 8; ++q) {
        bool g = (cw <= xc);
        cwk = g ? cw : cwk;
        chk = g ? chh : chk;
        wk = g ? we[q] : wk;
        hk = g ? hh[q] : hk;
        dk = g ? dd[q] : dk;
        dk1 = g ? dd[q + 1] : dk1;
        cw += we[q];
        chh += hh[q];
      }

      float th = (xc - cwk) / wk;
      float om = 1.f - th;
      float th2 = th * th, thom = th * om, om2 = om * om;
      float num = hk * (dk * th2 + dk1 * thom);
      float den = dk * th2 + 2.f * dk1 * thom + dk1 * om2;
      float yv = chk + num / den;
      float dn = dk1 * th2 + 2.f * dk * thom + dk * om2;
      float ld = 2.f * __logf(dn) - 2.f * __logf(den) + __logf(hk) - __logf(wk);

      xs[r][ch * 16 + f] = inside ? yv : xv;   // y in-place (own slot)
      ldacc[j] += inside ? ld : 0.f;
    }
  }

  // ---- ldet: butterfly reduce over the 16 f-lanes (width 16, same wave) ----
#pragma unroll
  for (int j = 0; j < 4; ++j) {
    float v = ldacc[j];
    v += __shfl_xor(v, 1);
    v += __shfl_xor(v, 2);
    v += __shfl_xor(v, 4);
    v += __shfl_xor(v, 8);
    if (f == 0) ldet[row0 + rgrp * 4 + j] = v;
  }
  __syncthreads();

  // ---- epilogue: coalesced y writes ----
  for (int i = t; i < ROWS * 64; i += NTHR) {
    int r = i >> 6, c = i & 63;
    out[(size_t)(row0 + r) * 64 + c] = xs[r][c];
  }
}

}  // namespace

extern "C" void kernel_launch(void* const* d_in, const int* in_sizes, int n_in,
                              void* d_out, int out_size, void* d_ws, size_t ws_size,
                              hipStream_t stream) {
  const float* x = (const float*)d_in[0];
  const float* W1 = (const float*)d_in[1];
  const float* b1 = (const float*)d_in[2];
  const float* W2 = (const float*)d_in[3];
  const float* b2 = (const float*)d_in[4];
  const float* W3 = (const float*)d_in[5];
  const float* b3 = (const float*)d_in[6];
  float* out = (float*)d_out;
  float* ldet = out + (size_t)65536 * 64;

  rqs_fused<<<dim3(65536 / ROWS), dim3(NTHR), 0, stream>>>(
      x, W1, b1, W2, b2, W3, b3, out, ldet);
}